// Round 7
// baseline (1821.959 us; speedup 1.0000x reference)
//
#include <hip/hip_runtime.h>
#include <hip/hip_bf16.h>
#include <math.h>

#define N_USERS 100000
#define N_ITEMS 50000
#define N_NODES 150000
#define NNZ     4800000
#define EMB     64
#define BATCH   4096
#define REG_C   1e-5f

// coarse bucketed counting sort
#define ROWB    512                 // rows per bucket (row >> 9)
#define NBK     293                 // ceil(150000/512)
#define PADC    17408               // slots/bucket = mean 16384 + 8 sigma
#define CSTRIDE 16                  // one cursor per 64B line
#define P1_EPB  8192                // edges per block in pass 1

static __device__ __forceinline__ unsigned short f2bf(float f) {
    unsigned u = __float_as_uint(f);
    u = u + 0x7FFFu + ((u >> 16) & 1u);
    return (unsigned short)(u >> 16);
}
static __device__ __forceinline__ unsigned pk2(float lo, float hi) {
    return (unsigned)f2bf(lo) | ((unsigned)f2bf(hi) << 16);
}
static __device__ __forceinline__ float blo(unsigned a) { return __uint_as_float(a << 16); }
static __device__ __forceinline__ float bhi(unsigned a) { return __uint_as_float(a & 0xFFFF0000u); }

// ---------------- pack ego = [user_emb; item_emb] -> Xh0 (bf16) -------------
__global__ void pack_kernel(const float* __restrict__ ue,
                            const float* __restrict__ ie,
                            unsigned int* __restrict__ xh) {
    int idx = blockIdx.x * 256 + threadIdx.x;     // one uint4 (8 dims) per thread
    if (idx >= N_NODES * 8) return;
    const float4* src;
    if (idx < N_USERS * 8) src = (const float4*)ue + (size_t)idx * 2;
    else src = (const float4*)ie + (size_t)(idx - N_USERS * 8) * 2;
    float4 a = src[0], b = src[1];
    uint4 h;
    h.x = pk2(a.x, a.y); h.y = pk2(a.z, a.w);
    h.z = pk2(b.x, b.y); h.w = pk2(b.z, b.w);
    ((uint4*)xh)[idx] = h;
}

// ---------------- cursor init ----------------
__global__ void initcur_kernel(int* __restrict__ gcursor) {
    int b = blockIdx.x * 256 + threadIdx.x;
    if (b < NBK) gcursor[b * CSTRIDE] = b * PADC;
}

// ---------------- pass 1: bin edges into coarse padded regions --------------
__global__ __launch_bounds__(256) void p1_bin_kernel(
    const int* __restrict__ rows, const int* __restrict__ cols,
    const float* __restrict__ vals, int* __restrict__ gcursor,
    int2* __restrict__ binned) {
    __shared__ int hist[NBK];
    __shared__ int base[NBK];
    int t = threadIdx.x;
    int e0 = blockIdx.x * P1_EPB;
    for (int b = t; b < NBK; b += 256) hist[b] = 0;
    __syncthreads();
    for (int i = 0; i < P1_EPB / 256; ++i) {
        int e = e0 + i * 256 + t;
        if (e < NNZ) atomicAdd(&hist[rows[e] >> 9], 1);
    }
    __syncthreads();
    for (int b = t; b < NBK; b += 256) {
        int h = hist[b];
        base[b] = (h > 0) ? atomicAdd(&gcursor[b * CSTRIDE], h) : 0;
        hist[b] = 0;                        // reuse as rank counter
    }
    __syncthreads();
    for (int i = 0; i < P1_EPB / 256; ++i) {
        int e = e0 + i * 256 + t;
        if (e < NNZ) {
            int r = rows[e];
            int b = r >> 9;
            int rk = atomicAdd(&hist[b], 1);
            int pos = base[b] + rk;
            if (pos < (b + 1) * PADC)       // overflow guard (P ~ 0)
                binned[pos] = make_int2(cols[e] | ((r & 511) << 18),
                                        __float_as_int(vals[e]));
        }
    }
}

// ---------------- pass 2: per-bucket row sort via global scatter ------------
__global__ __launch_bounds__(256) void p2_sort_kernel(
    const int* __restrict__ gcursor, const int2* __restrict__ binned,
    int2* __restrict__ csr, int* __restrict__ start, int* __restrict__ cnt) {
    __shared__ int hist[ROWB];
    __shared__ int excl[ROWB];
    int b = blockIdx.x;
    int t = threadIdx.x;
    int bbase = b * PADC;
    int n = gcursor[b * CSTRIDE] - bbase;
    if (n > PADC) n = PADC;
    hist[t] = 0; hist[t + 256] = 0;
    __syncthreads();
    for (int i = t; i < n; i += 256)
        atomicAdd(&hist[(binned[bbase + i].x >> 18) & 511], 1);
    __syncthreads();
    excl[t] = hist[t]; excl[t + 256] = hist[t + 256];
    __syncthreads();
    for (int o = 1; o < ROWB; o <<= 1) {           // Hillis-Steele inclusive, 512 wide
        int i1 = t + 256;
        int v0 = (t >= o) ? excl[t - o] : 0;
        int v1 = (i1 >= o) ? excl[i1 - o] : 0;
        __syncthreads();
        excl[t] += v0; excl[i1] += v1;
        __syncthreads();
    }
    int rowsInB = N_NODES - b * ROWB;
    if (rowsInB > ROWB) rowsInB = ROWB;
    for (int rr = t; rr < ROWB; rr += 256) {
        int s = excl[rr] - hist[rr];               // exclusive
        if (rr < rowsInB) {
            start[b * ROWB + rr] = bbase + s;
            cnt[b * ROWB + rr]   = hist[rr];
        }
        excl[rr] = s;                              // becomes local cursor
    }
    __syncthreads();
    for (int i = t; i < n; i += 256) {
        int2 rec = binned[bbase + i];
        int rl = (rec.x >> 18) & 511;
        int p = atomicAdd(&excl[rl], 1);
        csr[bbase + p] = make_int2(rec.x & 0x3FFFF, rec.y);
    }
}

// ---------------- fused: SpMM + dense + leakyrelu + row-norm ----------------
// Block = 64-row tile, 256 threads.  side_L lives only in LDS.
// Phase A: coalesced bf16 tile load -> xt.  Phase S: wave-per-row gather SpMM
// (predicated unroll-16) -> sl.  Phase D: lane=row, wave=dim-quarter dense,
// W rows wave-uniform.  Epilogue: row-norm, coalesced bf16 writeback.
__global__ __launch_bounds__(256) void fused_layer_kernel(
    const int* __restrict__ start, const int* __restrict__ cnt,
    const int2* __restrict__ edges,
    const unsigned int* __restrict__ xh_in,
    const float* __restrict__ W1, const float* __restrict__ b1,
    const float* __restrict__ W2, const float* __restrict__ b2,
    unsigned int* __restrict__ xh_out)
{
    __shared__ float xt[64 * 65];
    __shared__ float sl[64 * 65];
    __shared__ float psum[4 * 64];

    int t = threadIdx.x;
    int r0 = blockIdx.x * 64;

    // ---- Phase A: tile load xh_in -> xt (f32) ----
    #pragma unroll
    for (int i = 0; i < 2; ++i) {
        int q = i * 256 + t;                 // uint4 idx in tile (0..511)
        int row = q >> 3, colq = (q & 7) * 8;
        if (r0 + row < N_NODES) {
            uint4 h = ((const uint4*)xh_in)[(size_t)(r0 + row) * 8 + (q & 7)];
            int a = row * 65 + colq;
            xt[a + 0] = blo(h.x); xt[a + 1] = bhi(h.x);
            xt[a + 2] = blo(h.y); xt[a + 3] = bhi(h.y);
            xt[a + 4] = blo(h.z); xt[a + 5] = bhi(h.z);
            xt[a + 6] = blo(h.w); xt[a + 7] = bhi(h.w);
        }
    }

    // ---- Phase S: SpMM, wave per row ----
    int lane = t & 63;
    int wv = t >> 6;
    int half = lane >> 5;
    int p = lane & 31;
    for (int rep = 0; rep < 16; ++rep) {
        int rl_ = rep * 4 + wv;
        int row = r0 + rl_;
        if (row < N_NODES) {
            int s = start[row];
            int n = cnt[row];
            float accx = 0.f, accy = 0.f;
            for (int k = 0; k < n; k += 16) {
                #pragma unroll
                for (int j = 0; j < 8; ++j) {
                    int off = k + j * 2 + half;
                    bool valid = off < n;
                    int2 e = edges[s + (valid ? off : 0)];
                    unsigned a = xh_in[(size_t)e.x * 32 + p];
                    float v = valid ? __int_as_float(e.y) : 0.f;
                    accx = fmaf(v, blo(a), accx);
                    accy = fmaf(v, bhi(a), accy);
                }
            }
            accx += __shfl_xor(accx, 32, 64);
            accy += __shfl_xor(accy, 32, 64);
            if (half == 0) {
                sl[rl_ * 65 + 2 * p]     = accx;
                sl[rl_ * 65 + 2 * p + 1] = accy;
            }
        }
    }
    __syncthreads();

    // ---- Phase D: dense; lane = row, wave = output dim-quarter ----
    float acc[16];
    #pragma unroll
    for (int d = 0; d < 16; ++d) acc[d] = 0.f;
    const float* W1h = W1 + wv * 16;
    const float* W2h = W2 + wv * 16;
    #pragma unroll 4
    for (int e = 0; e < 64; ++e) {
        float xv = xt[lane * 65 + e];
        float sv = sl[lane * 65 + e];
        float sli = xv + sv;
        float pr  = xv * sv;
        const float* w1r = W1h + e * 64;     // wave-uniform
        const float* w2r = W2h + e * 64;     // wave-uniform
        #pragma unroll
        for (int d = 0; d < 16; ++d)
            acc[d] = fmaf(sli, w1r[d], fmaf(pr, w2r[d], acc[d]));
    }
    float lr[16];
    float ss = 0.f;
    #pragma unroll
    for (int d = 0; d < 16; ++d) {
        float v = acc[d] + b1[wv * 16 + d] + b2[wv * 16 + d];
        float l = v > 0.f ? v : 0.01f * v;
        lr[d] = l;
        ss += l * l;
    }
    psum[wv * 64 + lane] = ss;
    __syncthreads();                          // all xt/sl reads done
    #pragma unroll
    for (int d = 0; d < 16; ++d) sl[lane * 65 + wv * 16 + d] = lr[d];
    __syncthreads();

    // ---- writeback: coalesced bf16 ----
    #pragma unroll
    for (int i = 0; i < 2; ++i) {
        int q = i * 256 + t;
        int row = q >> 3, colq = (q & 7) * 8;
        if (r0 + row < N_NODES) {
            float s4 = psum[row] + psum[64 + row] + psum[128 + row] + psum[192 + row];
            float inv = 1.f / fmaxf(sqrtf(s4), 1e-12f);
            int a = row * 65 + colq;
            uint4 hh;
            hh.x = pk2(sl[a + 0] * inv, sl[a + 1] * inv);
            hh.y = pk2(sl[a + 2] * inv, sl[a + 3] * inv);
            hh.z = pk2(sl[a + 4] * inv, sl[a + 5] * inv);
            hh.w = pk2(sl[a + 6] * inv, sl[a + 7] * inv);
            ((uint4*)xh_out)[(size_t)(r0 + row) * 8 + (q & 7)] = hh;
        }
    }
}

// ---------------- layer-0 dot/L2 (exact f32 from inputs) --------------------
__global__ void acc0_kernel(const float* __restrict__ ue, const float* __restrict__ ie,
                            const int* __restrict__ u, const int* __restrict__ ii,
                            const int* __restrict__ jj,
                            float* __restrict__ dui, float* __restrict__ duj,
                            float* __restrict__ l2a) {
    int b = blockIdx.x * 4 + (threadIdx.x >> 6);
    int lane = threadIdx.x & 63;
    float uv = ue[(size_t)u[b] * 64 + lane];
    float pv = ie[(size_t)ii[b] * 64 + lane];
    float nv = ie[(size_t)jj[b] * 64 + lane];
    float a = uv * pv, c = uv * nv, l = uv * uv + pv * pv + nv * nv;
    #pragma unroll
    for (int o = 32; o > 0; o >>= 1) {
        a += __shfl_xor(a, o, 64);
        c += __shfl_xor(c, o, 64);
        l += __shfl_xor(l, o, 64);
    }
    if (lane == 0) { dui[b] = a; duj[b] = c; l2a[b] = l; }   // '=' : initializes
}

// ---------------- per-layer dot/L2 from bf16 embeddings ---------------------
__global__ void accB_kernel(const unsigned int* __restrict__ xh,
                            const int* __restrict__ u, const int* __restrict__ ii,
                            const int* __restrict__ jj,
                            float* __restrict__ dui, float* __restrict__ duj,
                            float* __restrict__ l2a) {
    int t = threadIdx.x;
    int lane = t & 63;
    int half = lane >> 5, p = lane & 31;
    int b = blockIdx.x * 8 + (t >> 6) * 2 + half;
    unsigned ua = xh[(size_t)u[b] * 32 + p];
    unsigned pa = xh[(size_t)(N_USERS + ii[b]) * 32 + p];
    unsigned na = xh[(size_t)(N_USERS + jj[b]) * 32 + p];
    float u0 = blo(ua), u1 = bhi(ua);
    float p0 = blo(pa), p1 = bhi(pa);
    float n0 = blo(na), n1 = bhi(na);
    float a = u0 * p0 + u1 * p1;
    float c = u0 * n0 + u1 * n1;
    float l = u0 * u0 + u1 * u1 + p0 * p0 + p1 * p1 + n0 * n0 + n1 * n1;
    #pragma unroll
    for (int o = 16; o > 0; o >>= 1) {       // reduce within each 32-lane half
        a += __shfl_xor(a, o, 64);
        c += __shfl_xor(c, o, 64);
        l += __shfl_xor(l, o, 64);
    }
    if (p == 0) { dui[b] += a; duj[b] += c; l2a[b] += l; }
}

// ---------------- final loss reduction --------------------------------------
__global__ void final_kernel(const float* __restrict__ dui, const float* __restrict__ duj,
                             const float* __restrict__ l2a, float* __restrict__ out) {
    __shared__ float sh[4];
    int t = threadIdx.x;
    float s = 0.f;
    for (int b = t; b < BATCH; b += 256) {
        float diff = dui[b] - duj[b];
        float ls = (diff >= 0.f) ? -log1pf(expf(-diff)) : (diff - log1pf(expf(diff)));
        s += -ls + REG_C * 0.5f * l2a[b];
    }
    #pragma unroll
    for (int o = 32; o > 0; o >>= 1) s += __shfl_xor(s, o, 64);
    int wave = t >> 6, lane = t & 63;
    if (lane == 0) sh[wave] = s;
    __syncthreads();
    if (t == 0) out[0] = (sh[0] + sh[1] + sh[2] + sh[3]) / (float)BATCH;
}

extern "C" void kernel_launch(void* const* d_in, const int* in_sizes, int n_in,
                              void* d_out, int out_size, void* d_ws, size_t ws_size,
                              hipStream_t stream) {
    const int*   rows     = (const int*)d_in[0];
    const int*   cols     = (const int*)d_in[1];
    const float* vals     = (const float*)d_in[2];
    const float* user_emb = (const float*)d_in[3];
    const float* item_emb = (const float*)d_in[4];
    const float* W_one    = (const float*)d_in[5];
    const float* b_one    = (const float*)d_in[6];
    const float* W_two    = (const float*)d_in[7];
    const float* b_two    = (const float*)d_in[8];
    const int*   u        = (const int*)d_in[9];
    const int*   ii       = (const int*)d_in[10];
    const int*   jj       = (const int*)d_in[11];

    // workspace (~122 MB)
    unsigned int* Xh0 = (unsigned int*)d_ws;                  // 4.8M u32 (19.2 MB)
    unsigned int* Xh1 = Xh0 + (size_t)N_NODES * 32;           // 4.8M u32
    int2* binned      = (int2*)(Xh1 + (size_t)N_NODES * 32);  // NBK*PADC int2 (40.8 MB)
    int2* csr         = binned + (size_t)NBK * PADC;          // NBK*PADC int2
    int*  gcursor     = (int*)(csr + (size_t)NBK * PADC);     // NBK*CSTRIDE
    int*  startA      = gcursor + NBK * CSTRIDE;              // 150,016
    int*  cntA        = startA + 150016;                      // 150,016
    float* dui        = (float*)(cntA + 150016);              // 4096
    float* duj        = dui + BATCH;
    float* l2a        = duj + BATCH;

    // CSR build (once; reused for all 3 layers)
    initcur_kernel<<<(NBK + 255) / 256, 256, 0, stream>>>(gcursor);
    p1_bin_kernel<<<(NNZ + P1_EPB - 1) / P1_EPB, 256, 0, stream>>>(rows, cols, vals, gcursor, binned);
    p2_sort_kernel<<<NBK, 256, 0, stream>>>(gcursor, binned, csr, startA, cntA);

    pack_kernel<<<(N_NODES * 8 + 255) / 256, 256, 0, stream>>>(user_emb, item_emb, Xh0);
    acc0_kernel<<<BATCH / 4, 256, 0, stream>>>(user_emb, item_emb, u, ii, jj, dui, duj, l2a);

    const int FG = (N_NODES + 63) / 64;
    unsigned int* xin = Xh0;
    unsigned int* xout = Xh1;
    for (int k = 0; k < 3; ++k) {
        fused_layer_kernel<<<FG, 256, 0, stream>>>(
            startA, cntA, csr, xin,
            W_one + k * 4096, b_one + k * 64,
            W_two + k * 4096, b_two + k * 64, xout);
        accB_kernel<<<BATCH / 8, 256, 0, stream>>>(xout, u, ii, jj, dui, duj, l2a);
        unsigned int* tmp = xin; xin = xout; xout = tmp;
    }

    final_kernel<<<1, 256, 0, stream>>>(dui, duj, l2a, (float*)d_out);
}

// Round 8
// 1193.965 us; speedup vs baseline: 1.5260x; 1.5260x over previous
//
#include <hip/hip_runtime.h>
#include <hip/hip_bf16.h>
#include <math.h>

#define N_USERS 100000
#define N_ITEMS 50000
#define N_NODES 150000
#define NNZ     4800000
#define EMB     64
#define BATCH   4096
#define REG_C   1e-5f

// coarse bucketed counting sort
#define ROWB    512                 // rows per bucket (row >> 9)
#define NBK     293                 // ceil(150000/512)
#define PADC    17408               // slots/bucket = mean 16384 + 8 sigma
#define CSTRIDE 16                  // one cursor per 64B line
#define P1_EPB  8192                // edges per block in pass 1

static __device__ __forceinline__ unsigned short f2bf(float f) {
    unsigned u = __float_as_uint(f);
    u = u + 0x7FFFu + ((u >> 16) & 1u);
    return (unsigned short)(u >> 16);
}
static __device__ __forceinline__ unsigned pk2(float lo, float hi) {
    return (unsigned)f2bf(lo) | ((unsigned)f2bf(hi) << 16);
}
static __device__ __forceinline__ float blo(unsigned a) { return __uint_as_float(a << 16); }
static __device__ __forceinline__ float bhi(unsigned a) { return __uint_as_float(a & 0xFFFF0000u); }

// nontemporal 8B edge load (edges are a pure stream: keep them out of L2)
static __device__ __forceinline__ void eload(const int2* p_, int& c, float& v) {
    unsigned long long w = __builtin_nontemporal_load((const unsigned long long*)p_);
    c = (int)(unsigned)(w & 0xFFFFFFFFu);
    v = __int_as_float((int)(unsigned)(w >> 32));
}

// ---------------- pack ego = [user_emb; item_emb] -> Xh0 (bf16) -------------
__global__ void pack_kernel(const float* __restrict__ ue,
                            const float* __restrict__ ie,
                            unsigned int* __restrict__ xh) {
    int idx = blockIdx.x * 256 + threadIdx.x;     // one uint4 (8 dims) per thread
    if (idx >= N_NODES * 8) return;
    const float4* src;
    if (idx < N_USERS * 8) src = (const float4*)ue + (size_t)idx * 2;
    else src = (const float4*)ie + (size_t)(idx - N_USERS * 8) * 2;
    float4 a = src[0], b = src[1];
    uint4 h;
    h.x = pk2(a.x, a.y); h.y = pk2(a.z, a.w);
    h.z = pk2(b.x, b.y); h.w = pk2(b.z, b.w);
    ((uint4*)xh)[idx] = h;
}

// ---------------- cursor init ----------------
__global__ void initcur_kernel(int* __restrict__ gcursor) {
    int b = blockIdx.x * 256 + threadIdx.x;
    if (b < NBK) gcursor[b * CSTRIDE] = b * PADC;
}

// ---------------- pass 1: bin edges into coarse padded regions --------------
__global__ __launch_bounds__(256) void p1_bin_kernel(
    const int* __restrict__ rows, const int* __restrict__ cols,
    const float* __restrict__ vals, int* __restrict__ gcursor,
    int2* __restrict__ binned) {
    __shared__ int hist[NBK];
    __shared__ int base[NBK];
    int t = threadIdx.x;
    int e0 = blockIdx.x * P1_EPB;
    for (int b = t; b < NBK; b += 256) hist[b] = 0;
    __syncthreads();
    for (int i = 0; i < P1_EPB / 256; ++i) {
        int e = e0 + i * 256 + t;
        if (e < NNZ) atomicAdd(&hist[rows[e] >> 9], 1);
    }
    __syncthreads();
    for (int b = t; b < NBK; b += 256) {
        int h = hist[b];
        base[b] = (h > 0) ? atomicAdd(&gcursor[b * CSTRIDE], h) : 0;
        hist[b] = 0;                        // reuse as rank counter
    }
    __syncthreads();
    for (int i = 0; i < P1_EPB / 256; ++i) {
        int e = e0 + i * 256 + t;
        if (e < NNZ) {
            int r = rows[e];
            int b = r >> 9;
            int rk = atomicAdd(&hist[b], 1);
            int pos = base[b] + rk;
            if (pos < (b + 1) * PADC)       // overflow guard (P ~ 0)
                binned[pos] = make_int2(cols[e] | ((r & 511) << 18),
                                        __float_as_int(vals[e]));
        }
    }
}

// ---------------- pass 2: per-bucket row sort via global scatter ------------
__global__ __launch_bounds__(256) void p2_sort_kernel(
    const int* __restrict__ gcursor, const int2* __restrict__ binned,
    int2* __restrict__ csr, int* __restrict__ start, int* __restrict__ cnt) {
    __shared__ int hist[ROWB];
    __shared__ int excl[ROWB];
    int b = blockIdx.x;
    int t = threadIdx.x;
    int bbase = b * PADC;
    int n = gcursor[b * CSTRIDE] - bbase;
    if (n > PADC) n = PADC;
    hist[t] = 0; hist[t + 256] = 0;
    __syncthreads();
    for (int i = t; i < n; i += 256)
        atomicAdd(&hist[(binned[bbase + i].x >> 18) & 511], 1);
    __syncthreads();
    excl[t] = hist[t]; excl[t + 256] = hist[t + 256];
    __syncthreads();
    for (int o = 1; o < ROWB; o <<= 1) {           // Hillis-Steele inclusive, 512 wide
        int i1 = t + 256;
        int v0 = (t >= o) ? excl[t - o] : 0;
        int v1 = (i1 >= o) ? excl[i1 - o] : 0;
        __syncthreads();
        excl[t] += v0; excl[i1] += v1;
        __syncthreads();
    }
    int rowsInB = N_NODES - b * ROWB;
    if (rowsInB > ROWB) rowsInB = ROWB;
    for (int rr = t; rr < ROWB; rr += 256) {
        int s = excl[rr] - hist[rr];               // exclusive
        if (rr < rowsInB) {
            start[b * ROWB + rr] = bbase + s;
            cnt[b * ROWB + rr]   = hist[rr];
        }
        excl[rr] = s;                              // becomes local cursor
    }
    __syncthreads();
    for (int i = t; i < n; i += 256) {
        int2 rec = binned[bbase + i];
        int rl = (rec.x >> 18) & 511;
        int p = atomicAdd(&excl[rl], 1);
        csr[bbase + p] = make_int2(rec.x & 0x3FFFF, rec.y);
    }
}

// ---------------- CSR SpMM: wave/row, bf16 gathers, 16 edges in flight ------
__global__ __launch_bounds__(256) void spmm_csr_kernel(
    const int* __restrict__ start, const int* __restrict__ cnt,
    const int2* __restrict__ edges, const unsigned int* __restrict__ xh,
    float* __restrict__ out) {
    int row = blockIdx.x * 4 + (threadIdx.x >> 6);
    if (row >= N_NODES) return;
    int lane = threadIdx.x & 63;
    int half = lane >> 5;
    int p    = lane & 31;
    int s = start[row];
    int n = cnt[row];
    float accx = 0.f, accy = 0.f;
    int k = 0;
    for (; k + 16 <= n; k += 16) {
        int c[8]; float v[8];
        #pragma unroll
        for (int j = 0; j < 8; ++j) eload(&edges[s + k + 2 * j + half], c[j], v[j]);
        #pragma unroll
        for (int j = 0; j < 8; ++j) {
            unsigned a = xh[(size_t)c[j] * 32 + p];
            accx = fmaf(v[j], blo(a), accx);
            accy = fmaf(v[j], bhi(a), accy);
        }
    }
    for (; k + 4 <= n; k += 4) {
        int c0, c1; float v0, v1;
        eload(&edges[s + k + half], c0, v0);
        eload(&edges[s + k + 2 + half], c1, v1);
        unsigned a0 = xh[(size_t)c0 * 32 + p];
        unsigned a1 = xh[(size_t)c1 * 32 + p];
        accx = fmaf(v0, blo(a0), accx); accy = fmaf(v0, bhi(a0), accy);
        accx = fmaf(v1, blo(a1), accx); accy = fmaf(v1, bhi(a1), accy);
    }
    for (; k + 2 <= n; k += 2) {
        int c0; float v0;
        eload(&edges[s + k + half], c0, v0);
        unsigned a = xh[(size_t)c0 * 32 + p];
        accx = fmaf(v0, blo(a), accx); accy = fmaf(v0, bhi(a), accy);
    }
    if (k < n) {                               // single leftover edge
        int c0; float v0;
        eload(&edges[s + k], c0, v0);
        unsigned a = xh[(size_t)c0 * 32 + p];
        float v = (half == 0) ? v0 : 0.f;
        accx = fmaf(v, blo(a), accx); accy = fmaf(v, bhi(a), accy);
    }
    accx += __shfl_xor(accx, 32, 64);
    accy += __shfl_xor(accy, 32, 64);
    if (half == 0)
        ((float2*)out)[(size_t)row * 32 + p] = make_float2(accx, accy);
}

// ---------------- dense: LDS-tiled; bf16 x in, f32 sideL in, bf16 out -------
__global__ __launch_bounds__(256) void dense_kernel(
    const unsigned int* __restrict__ xh_in, const float* __restrict__ sideL,
    const float* __restrict__ W1, const float* __restrict__ b1,
    const float* __restrict__ W2, const float* __restrict__ b2,
    unsigned int* __restrict__ xh_out)
{
    __shared__ float xt[64 * 65];
    __shared__ float sl[64 * 65];
    __shared__ float psum[4 * 64];

    int t = threadIdx.x;
    int r0 = blockIdx.x * 64;

    // ---- Phase A: coalesced tile loads ----
    #pragma unroll
    for (int i = 0; i < 2; ++i) {
        int q = i * 256 + t;                 // uint4 idx in tile (0..511)
        int row = q >> 3, colq = (q & 7) * 8;
        if (r0 + row < N_NODES) {
            uint4 h = ((const uint4*)xh_in)[(size_t)(r0 + row) * 8 + (q & 7)];
            int a = row * 65 + colq;
            xt[a + 0] = blo(h.x); xt[a + 1] = bhi(h.x);
            xt[a + 2] = blo(h.y); xt[a + 3] = bhi(h.y);
            xt[a + 4] = blo(h.z); xt[a + 5] = bhi(h.z);
            xt[a + 6] = blo(h.w); xt[a + 7] = bhi(h.w);
        }
    }
    #pragma unroll
    for (int i = 0; i < 4; ++i) {
        int q = i * 256 + t;                 // float4 idx in tile (0..1023)
        int row = q >> 4, col = (q & 15) * 4;
        if (r0 + row < N_NODES) {
            float4 sv = ((const float4*)sideL)[(size_t)r0 * 16 + q];
            int a = row * 65 + col;
            sl[a + 0] = sv.x; sl[a + 1] = sv.y; sl[a + 2] = sv.z; sl[a + 3] = sv.w;
        }
    }
    __syncthreads();

    // ---- Phase D: lane = row, wave = output dim-quarter ----
    int lane = t & 63;
    int wv = t >> 6;
    float acc[16];
    #pragma unroll
    for (int d = 0; d < 16; ++d) acc[d] = 0.f;
    const float* W1h = W1 + wv * 16;
    const float* W2h = W2 + wv * 16;
    #pragma unroll 4
    for (int e = 0; e < 64; ++e) {
        float xv = xt[lane * 65 + e];
        float sv = sl[lane * 65 + e];
        float sli = xv + sv;
        float pr  = xv * sv;
        const float* w1r = W1h + e * 64;     // wave-uniform
        const float* w2r = W2h + e * 64;     // wave-uniform
        #pragma unroll
        for (int d = 0; d < 16; ++d)
            acc[d] = fmaf(sli, w1r[d], fmaf(pr, w2r[d], acc[d]));
    }
    float lr[16];
    float ss = 0.f;
    #pragma unroll
    for (int d = 0; d < 16; ++d) {
        float v = acc[d] + b1[wv * 16 + d] + b2[wv * 16 + d];
        float l = v > 0.f ? v : 0.01f * v;
        lr[d] = l;
        ss += l * l;
    }
    psum[wv * 64 + lane] = ss;
    __syncthreads();                          // all xt/sl reads done
    #pragma unroll
    for (int d = 0; d < 16; ++d) sl[lane * 65 + wv * 16 + d] = lr[d];
    __syncthreads();

    // ---- writeback: coalesced bf16 ----
    #pragma unroll
    for (int i = 0; i < 2; ++i) {
        int q = i * 256 + t;
        int row = q >> 3, colq = (q & 7) * 8;
        if (r0 + row < N_NODES) {
            float s4 = psum[row] + psum[64 + row] + psum[128 + row] + psum[192 + row];
            float inv = 1.f / fmaxf(sqrtf(s4), 1e-12f);
            int a = row * 65 + colq;
            uint4 hh;
            hh.x = pk2(sl[a + 0] * inv, sl[a + 1] * inv);
            hh.y = pk2(sl[a + 2] * inv, sl[a + 3] * inv);
            hh.z = pk2(sl[a + 4] * inv, sl[a + 5] * inv);
            hh.w = pk2(sl[a + 6] * inv, sl[a + 7] * inv);
            ((uint4*)xh_out)[(size_t)(r0 + row) * 8 + (q & 7)] = hh;
        }
    }
}

// ---------------- layer-0 dot/L2 (exact f32 from inputs; initializes) -------
__global__ void acc0_kernel(const float* __restrict__ ue, const float* __restrict__ ie,
                            const int* __restrict__ u, const int* __restrict__ ii,
                            const int* __restrict__ jj,
                            float* __restrict__ dui, float* __restrict__ duj,
                            float* __restrict__ l2a) {
    int b = blockIdx.x * 4 + (threadIdx.x >> 6);
    int lane = threadIdx.x & 63;
    float uv = ue[(size_t)u[b] * 64 + lane];
    float pv = ie[(size_t)ii[b] * 64 + lane];
    float nv = ie[(size_t)jj[b] * 64 + lane];
    float a = uv * pv, c = uv * nv, l = uv * uv + pv * pv + nv * nv;
    #pragma unroll
    for (int o = 32; o > 0; o >>= 1) {
        a += __shfl_xor(a, o, 64);
        c += __shfl_xor(c, o, 64);
        l += __shfl_xor(l, o, 64);
    }
    if (lane == 0) { dui[b] = a; duj[b] = c; l2a[b] = l; }
}

// ---------------- per-layer dot/L2 from bf16 embeddings ---------------------
__global__ void accB_kernel(const unsigned int* __restrict__ xh,
                            const int* __restrict__ u, const int* __restrict__ ii,
                            const int* __restrict__ jj,
                            float* __restrict__ dui, float* __restrict__ duj,
                            float* __restrict__ l2a) {
    int t = threadIdx.x;
    int lane = t & 63;
    int half = lane >> 5, p = lane & 31;
    int b = blockIdx.x * 8 + (t >> 6) * 2 + half;
    unsigned ua = xh[(size_t)u[b] * 32 + p];
    unsigned pa = xh[(size_t)(N_USERS + ii[b]) * 32 + p];
    unsigned na = xh[(size_t)(N_USERS + jj[b]) * 32 + p];
    float u0 = blo(ua), u1 = bhi(ua);
    float p0 = blo(pa), p1 = bhi(pa);
    float n0 = blo(na), n1 = bhi(na);
    float a = u0 * p0 + u1 * p1;
    float c = u0 * n0 + u1 * n1;
    float l = u0 * u0 + u1 * u1 + p0 * p0 + p1 * p1 + n0 * n0 + n1 * n1;
    #pragma unroll
    for (int o = 16; o > 0; o >>= 1) {       // reduce within each 32-lane half
        a += __shfl_xor(a, o, 64);
        c += __shfl_xor(c, o, 64);
        l += __shfl_xor(l, o, 64);
    }
    if (p == 0) { dui[b] += a; duj[b] += c; l2a[b] += l; }
}

// ---------------- final loss reduction --------------------------------------
__global__ void final_kernel(const float* __restrict__ dui, const float* __restrict__ duj,
                             const float* __restrict__ l2a, float* __restrict__ out) {
    __shared__ float sh[4];
    int t = threadIdx.x;
    float s = 0.f;
    for (int b = t; b < BATCH; b += 256) {
        float diff = dui[b] - duj[b];
        float ls = (diff >= 0.f) ? -log1pf(expf(-diff)) : (diff - log1pf(expf(diff)));
        s += -ls + REG_C * 0.5f * l2a[b];
    }
    #pragma unroll
    for (int o = 32; o > 0; o >>= 1) s += __shfl_xor(s, o, 64);
    int wave = t >> 6, lane = t & 63;
    if (lane == 0) sh[wave] = s;
    __syncthreads();
    if (t == 0) out[0] = (sh[0] + sh[1] + sh[2] + sh[3]) / (float)BATCH;
}

extern "C" void kernel_launch(void* const* d_in, const int* in_sizes, int n_in,
                              void* d_out, int out_size, void* d_ws, size_t ws_size,
                              hipStream_t stream) {
    const int*   rows     = (const int*)d_in[0];
    const int*   cols     = (const int*)d_in[1];
    const float* vals     = (const float*)d_in[2];
    const float* user_emb = (const float*)d_in[3];
    const float* item_emb = (const float*)d_in[4];
    const float* W_one    = (const float*)d_in[5];
    const float* b_one    = (const float*)d_in[6];
    const float* W_two    = (const float*)d_in[7];
    const float* b_two    = (const float*)d_in[8];
    const int*   u        = (const int*)d_in[9];
    const int*   ii       = (const int*)d_in[10];
    const int*   jj       = (const int*)d_in[11];

    // workspace (~122 MB).  B (f32 sideL, 38.4 MB) aliases binned (40.8 MB),
    // which is dead after p2_sort.
    unsigned int* Xh0 = (unsigned int*)d_ws;                  // 19.2 MB
    unsigned int* Xh1 = Xh0 + (size_t)N_NODES * 32;           // 19.2 MB
    int2* binned      = (int2*)(Xh1 + (size_t)N_NODES * 32);  // 40.8 MB
    float* B          = (float*)binned;                       // alias (post-p2)
    int2* csr         = binned + (size_t)NBK * PADC;          // 40.8 MB
    int*  gcursor     = (int*)(csr + (size_t)NBK * PADC);
    int*  startA      = gcursor + NBK * CSTRIDE;              // 150,016
    int*  cntA        = startA + 150016;                      // 150,016
    float* dui        = (float*)(cntA + 150016);              // 4096
    float* duj        = dui + BATCH;
    float* l2a        = duj + BATCH;

    // CSR build (once; reused for all 3 layers)
    initcur_kernel<<<(NBK + 255) / 256, 256, 0, stream>>>(gcursor);
    p1_bin_kernel<<<(NNZ + P1_EPB - 1) / P1_EPB, 256, 0, stream>>>(rows, cols, vals, gcursor, binned);
    p2_sort_kernel<<<NBK, 256, 0, stream>>>(gcursor, binned, csr, startA, cntA);

    pack_kernel<<<(N_NODES * 8 + 255) / 256, 256, 0, stream>>>(user_emb, item_emb, Xh0);
    acc0_kernel<<<BATCH / 4, 256, 0, stream>>>(user_emb, item_emb, u, ii, jj, dui, duj, l2a);

    unsigned int* xin = Xh0;
    unsigned int* xout = Xh1;
    for (int k = 0; k < 3; ++k) {
        spmm_csr_kernel<<<(N_NODES + 3) / 4, 256, 0, stream>>>(startA, cntA, csr, xin, B);
        dense_kernel<<<(N_NODES + 63) / 64, 256, 0, stream>>>(
            xin, B, W_one + k * 4096, b_one + k * 64,
            W_two + k * 4096, b_two + k * 64, xout);
        accB_kernel<<<BATCH / 8, 256, 0, stream>>>(xout, u, ii, jj, dui, duj, l2a);
        unsigned int* tmp = xin; xin = xout; xout = tmp;
    }

    final_kernel<<<1, 256, 0, stream>>>(dui, duj, l2a, (float*)d_out);
}

// Round 9
// 800.026 us; speedup vs baseline: 2.2774x; 1.4924x over previous
//
#include <hip/hip_runtime.h>
#include <hip/hip_bf16.h>
#include <math.h>

#define N_USERS 100000
#define N_ITEMS 50000
#define N_NODES 150000
#define NNZ     4800000
#define EMB     64
#define BATCH   4096
#define REG_C   1e-5f

// coarse bucketed counting sort
#define ROWB    512                 // rows per bucket (row >> 9)
#define NBK     293                 // ceil(150000/512)
#define PADC    17408               // slots/bucket = mean 16384 + 8 sigma
#define CSTRIDE 16                  // one cursor per 64B line
#define P1_EPB  8192                // edges per block in pass 1

#define LROW    36                  // LDS row stride in uints (16B-aligned rows)

typedef short short8 __attribute__((ext_vector_type(8)));
typedef float f32x4  __attribute__((ext_vector_type(4)));

static __device__ __forceinline__ unsigned short f2bf(float f) {
    unsigned u = __float_as_uint(f);
    u = u + 0x7FFFu + ((u >> 16) & 1u);
    return (unsigned short)(u >> 16);
}
static __device__ __forceinline__ unsigned pk2(float lo, float hi) {
    return (unsigned)f2bf(lo) | ((unsigned)f2bf(hi) << 16);
}
static __device__ __forceinline__ float blo(unsigned a) { return __uint_as_float(a << 16); }
static __device__ __forceinline__ float bhi(unsigned a) { return __uint_as_float(a & 0xFFFF0000u); }

// nontemporal 8B edge load (edges are a pure stream: keep them out of L2)
static __device__ __forceinline__ void eload(const int2* p_, int& c, float& v) {
    unsigned long long w = __builtin_nontemporal_load((const unsigned long long*)p_);
    c = (int)(unsigned)(w & 0xFFFFFFFFu);
    v = __int_as_float((int)(unsigned)(w >> 32));
}

// ---------------- pack ego = [user_emb; item_emb] -> Xh0 (bf16) -------------
__global__ void pack_kernel(const float* __restrict__ ue,
                            const float* __restrict__ ie,
                            unsigned int* __restrict__ xh) {
    int idx = blockIdx.x * 256 + threadIdx.x;     // one uint4 (8 dims) per thread
    if (idx >= N_NODES * 8) return;
    const float4* src;
    if (idx < N_USERS * 8) src = (const float4*)ue + (size_t)idx * 2;
    else src = (const float4*)ie + (size_t)(idx - N_USERS * 8) * 2;
    float4 a = src[0], b = src[1];
    uint4 h;
    h.x = pk2(a.x, a.y); h.y = pk2(a.z, a.w);
    h.z = pk2(b.x, b.y); h.w = pk2(b.z, b.w);
    ((uint4*)xh)[idx] = h;
}

// ---------------- cursor init ----------------
__global__ void initcur_kernel(int* __restrict__ gcursor) {
    int b = blockIdx.x * 256 + threadIdx.x;
    if (b < NBK) gcursor[b * CSTRIDE] = b * PADC;
}

// ---------------- pass 1: bin edges into coarse padded regions --------------
__global__ __launch_bounds__(256) void p1_bin_kernel(
    const int* __restrict__ rows, const int* __restrict__ cols,
    const float* __restrict__ vals, int* __restrict__ gcursor,
    int2* __restrict__ binned) {
    __shared__ int hist[NBK];
    __shared__ int base[NBK];
    int t = threadIdx.x;
    int e0 = blockIdx.x * P1_EPB;
    for (int b = t; b < NBK; b += 256) hist[b] = 0;
    __syncthreads();
    for (int i = 0; i < P1_EPB / 256; ++i) {
        int e = e0 + i * 256 + t;
        if (e < NNZ) atomicAdd(&hist[rows[e] >> 9], 1);
    }
    __syncthreads();
    for (int b = t; b < NBK; b += 256) {
        int h = hist[b];
        base[b] = (h > 0) ? atomicAdd(&gcursor[b * CSTRIDE], h) : 0;
        hist[b] = 0;                        // reuse as rank counter
    }
    __syncthreads();
    for (int i = 0; i < P1_EPB / 256; ++i) {
        int e = e0 + i * 256 + t;
        if (e < NNZ) {
            int r = rows[e];
            int b = r >> 9;
            int rk = atomicAdd(&hist[b], 1);
            int pos = base[b] + rk;
            if (pos < (b + 1) * PADC)       // overflow guard (P ~ 0)
                binned[pos] = make_int2(cols[e] | ((r & 511) << 18),
                                        __float_as_int(vals[e]));
        }
    }
}

// ---------------- pass 2: per-bucket row sort via global scatter ------------
__global__ __launch_bounds__(256) void p2_sort_kernel(
    const int* __restrict__ gcursor, const int2* __restrict__ binned,
    int2* __restrict__ csr, int* __restrict__ start, int* __restrict__ cnt) {
    __shared__ int hist[ROWB];
    __shared__ int excl[ROWB];
    int b = blockIdx.x;
    int t = threadIdx.x;
    int bbase = b * PADC;
    int n = gcursor[b * CSTRIDE] - bbase;
    if (n > PADC) n = PADC;
    hist[t] = 0; hist[t + 256] = 0;
    __syncthreads();
    for (int i = t; i < n; i += 256)
        atomicAdd(&hist[(binned[bbase + i].x >> 18) & 511], 1);
    __syncthreads();
    excl[t] = hist[t]; excl[t + 256] = hist[t + 256];
    __syncthreads();
    for (int o = 1; o < ROWB; o <<= 1) {           // Hillis-Steele inclusive, 512 wide
        int i1 = t + 256;
        int v0 = (t >= o) ? excl[t - o] : 0;
        int v1 = (i1 >= o) ? excl[i1 - o] : 0;
        __syncthreads();
        excl[t] += v0; excl[i1] += v1;
        __syncthreads();
    }
    int rowsInB = N_NODES - b * ROWB;
    if (rowsInB > ROWB) rowsInB = ROWB;
    for (int rr = t; rr < ROWB; rr += 256) {
        int s = excl[rr] - hist[rr];               // exclusive
        if (rr < rowsInB) {
            start[b * ROWB + rr] = bbase + s;
            cnt[b * ROWB + rr]   = hist[rr];
        }
        excl[rr] = s;                              // becomes local cursor
    }
    __syncthreads();
    for (int i = t; i < n; i += 256) {
        int2 rec = binned[bbase + i];
        int rl = (rec.x >> 18) & 511;
        int p = atomicAdd(&excl[rl], 1);
        csr[bbase + p] = make_int2(rec.x & 0x3FFFF, rec.y);
    }
}

// ---------------- CSR SpMM: wave/row, bf16 gathers, 16 edges in flight ------
__global__ __launch_bounds__(256) void spmm_csr_kernel(
    const int* __restrict__ start, const int* __restrict__ cnt,
    const int2* __restrict__ edges, const unsigned int* __restrict__ xh,
    float* __restrict__ out) {
    int row = blockIdx.x * 4 + (threadIdx.x >> 6);
    if (row >= N_NODES) return;
    int lane = threadIdx.x & 63;
    int half = lane >> 5;
    int p    = lane & 31;
    int s = start[row];
    int n = cnt[row];
    float accx = 0.f, accy = 0.f;
    int k = 0;
    for (; k + 16 <= n; k += 16) {
        int c[8]; float v[8];
        #pragma unroll
        for (int j = 0; j < 8; ++j) eload(&edges[s + k + 2 * j + half], c[j], v[j]);
        #pragma unroll
        for (int j = 0; j < 8; ++j) {
            unsigned a = xh[(size_t)c[j] * 32 + p];
            accx = fmaf(v[j], blo(a), accx);
            accy = fmaf(v[j], bhi(a), accy);
        }
    }
    for (; k + 4 <= n; k += 4) {
        int c0, c1; float v0, v1;
        eload(&edges[s + k + half], c0, v0);
        eload(&edges[s + k + 2 + half], c1, v1);
        unsigned a0 = xh[(size_t)c0 * 32 + p];
        unsigned a1 = xh[(size_t)c1 * 32 + p];
        accx = fmaf(v0, blo(a0), accx); accy = fmaf(v0, bhi(a0), accy);
        accx = fmaf(v1, blo(a1), accx); accy = fmaf(v1, bhi(a1), accy);
    }
    for (; k + 2 <= n; k += 2) {
        int c0; float v0;
        eload(&edges[s + k + half], c0, v0);
        unsigned a = xh[(size_t)c0 * 32 + p];
        accx = fmaf(v0, blo(a), accx); accy = fmaf(v0, bhi(a), accy);
    }
    if (k < n) {                               // single leftover edge
        int c0; float v0;
        eload(&edges[s + k], c0, v0);
        unsigned a = xh[(size_t)c0 * 32 + p];
        float v = (half == 0) ? v0 : 0.f;
        accx = fmaf(v, blo(a), accx); accy = fmaf(v, bhi(a), accy);
    }
    accx += __shfl_xor(accx, 32, 64);
    accy += __shfl_xor(accy, 32, 64);
    if (half == 0)
        ((float2*)out)[(size_t)row * 32 + p] = make_float2(accx, accy);
}

// ---------------- dense v4: MFMA.  OUT = leakyrelu(SLI@W1 + PR@W2 + b) ------
// Block = 64-row tile, 4 waves; wave w owns out rows [16w,16w+16).
// SLI/PR staged as packed bf16 in LDS; W1/W2 staged transposed [n][k] bf16.
// Fragments: A[m=lane&15][k=quad*8+j] (m120-verified), C/D col=lane&15,
// row=quad*4+reg (m89/m91-verified).  16 mfma_f32_16x16x32_bf16 per wave.
__global__ __launch_bounds__(256) void dense_kernel(
    const unsigned int* __restrict__ xh_in, const float* __restrict__ sideL,
    const float* __restrict__ W1, const float* __restrict__ b1,
    const float* __restrict__ W2, const float* __restrict__ b2,
    unsigned int* __restrict__ xh_out)
{
    __shared__ unsigned asl[64 * LROW];   // SLI bf16 pairs
    __shared__ unsigned apr[64 * LROW];   // PR  bf16 pairs
    __shared__ unsigned wt1[64 * LROW];   // W1^T [n][k]; reused as out-stage
    __shared__ unsigned wt2[64 * LROW];   // W2^T [n][k]

    int t = threadIdx.x;
    int r0 = blockIdx.x * 64;

    // ---- stage W1/W2 transposed to bf16 [n][k] ----
    #pragma unroll
    for (int i = 0; i < 4; ++i) {
        int idx = i * 256 + t;               // 0..1023 float4s
        int kk = idx >> 4;                   // k row 0..63
        int ng = idx & 15;                   // col group: cols 4ng..4ng+3
        float4 w1v = ((const float4*)W1)[idx];
        float4 w2v = ((const float4*)W2)[idx];
        unsigned short* s1 = (unsigned short*)wt1;
        unsigned short* s2 = (unsigned short*)wt2;
        int c0 = 4 * ng;
        s1[(c0 + 0) * (2 * LROW) + kk] = f2bf(w1v.x);
        s1[(c0 + 1) * (2 * LROW) + kk] = f2bf(w1v.y);
        s1[(c0 + 2) * (2 * LROW) + kk] = f2bf(w1v.z);
        s1[(c0 + 3) * (2 * LROW) + kk] = f2bf(w1v.w);
        s2[(c0 + 0) * (2 * LROW) + kk] = f2bf(w2v.x);
        s2[(c0 + 1) * (2 * LROW) + kk] = f2bf(w2v.y);
        s2[(c0 + 2) * (2 * LROW) + kk] = f2bf(w2v.z);
        s2[(c0 + 3) * (2 * LROW) + kk] = f2bf(w2v.w);
    }

    // ---- stage SLI / PR (bf16 packed) ----
    #pragma unroll
    for (int i = 0; i < 2; ++i) {
        int q = i * 256 + t;                 // 0..511
        int row = q >> 3;                    // 0..63
        int u4 = q & 7;                      // uint4 within row
        uint4 h = make_uint4(0, 0, 0, 0);
        float4 s0 = make_float4(0.f, 0.f, 0.f, 0.f);
        float4 s1 = make_float4(0.f, 0.f, 0.f, 0.f);
        if (r0 + row < N_NODES) {
            h  = ((const uint4*)xh_in)[(size_t)(r0 + row) * 8 + u4];
            s0 = ((const float4*)sideL)[(size_t)(r0 + row) * 16 + 2 * u4];
            s1 = ((const float4*)sideL)[(size_t)(r0 + row) * 16 + 2 * u4 + 1];
        }
        float x0 = blo(h.x), x1 = bhi(h.x), x2 = blo(h.y), x3 = bhi(h.y);
        float x4 = blo(h.z), x5 = bhi(h.z), x6 = blo(h.w), x7 = bhi(h.w);
        uint4 sa, pa;
        sa.x = pk2(x0 + s0.x, x1 + s0.y); sa.y = pk2(x2 + s0.z, x3 + s0.w);
        sa.z = pk2(x4 + s1.x, x5 + s1.y); sa.w = pk2(x6 + s1.z, x7 + s1.w);
        pa.x = pk2(x0 * s0.x, x1 * s0.y); pa.y = pk2(x2 * s0.z, x3 * s0.w);
        pa.z = pk2(x4 * s1.x, x5 * s1.y); pa.w = pk2(x6 * s1.z, x7 * s1.w);
        *(uint4*)&asl[row * LROW + 4 * u4] = sa;
        *(uint4*)&apr[row * LROW + 4 * u4] = pa;
    }
    __syncthreads();

    // ---- MFMA phase ----
    int l = t & 63, wv = t >> 6;
    int q4 = l >> 4, mr = l & 15;
    int abase = (wv * 16 + mr) * LROW + 4 * q4;
    short8 aS0 = *(const short8*)&asl[abase];
    short8 aS1 = *(const short8*)&asl[abase + 16];
    short8 aP0 = *(const short8*)&apr[abase];
    short8 aP1 = *(const short8*)&apr[abase + 16];

    float lr[4][4];
    float rowss[4] = {0.f, 0.f, 0.f, 0.f};
    #pragma unroll
    for (int nb = 0; nb < 4; ++nb) {
        int wbase = (nb * 16 + mr) * LROW + 4 * q4;
        short8 b10 = *(const short8*)&wt1[wbase];
        short8 b11 = *(const short8*)&wt1[wbase + 16];
        short8 b20 = *(const short8*)&wt2[wbase];
        short8 b21 = *(const short8*)&wt2[wbase + 16];
        f32x4 acc = {0.f, 0.f, 0.f, 0.f};
        acc = __builtin_amdgcn_mfma_f32_16x16x32_bf16(aS0, b10, acc, 0, 0, 0);
        acc = __builtin_amdgcn_mfma_f32_16x16x32_bf16(aS1, b11, acc, 0, 0, 0);
        acc = __builtin_amdgcn_mfma_f32_16x16x32_bf16(aP0, b20, acc, 0, 0, 0);
        acc = __builtin_amdgcn_mfma_f32_16x16x32_bf16(aP1, b21, acc, 0, 0, 0);
        float bias = b1[nb * 16 + mr] + b2[nb * 16 + mr];
        #pragma unroll
        for (int r = 0; r < 4; ++r) {
            float v = acc[r] + bias;
            float lrv = v > 0.f ? v : 0.01f * v;
            lr[nb][r] = lrv;
            rowss[r] += lrv * lrv;
        }
    }
    // row-sums across the 16 lanes of each quad (full 64-col sum per row)
    #pragma unroll
    for (int o = 1; o < 16; o <<= 1) {
        #pragma unroll
        for (int r = 0; r < 4; ++r) rowss[r] += __shfl_xor(rowss[r], o, 64);
    }
    float inv[4];
    #pragma unroll
    for (int r = 0; r < 4; ++r) inv[r] = 1.f / fmaxf(sqrtf(rowss[r]), 1e-12f);

    __syncthreads();                         // all wt1/wt2 reads done
    // ---- stage normalized bf16 out (reuse wt1) ----
    unsigned short* os = (unsigned short*)wt1;
    #pragma unroll
    for (int nb = 0; nb < 4; ++nb) {
        #pragma unroll
        for (int r = 0; r < 4; ++r) {
            int rloc = wv * 16 + q4 * 4 + r;
            os[rloc * (2 * LROW) + nb * 16 + mr] = f2bf(lr[nb][r] * inv[r]);
        }
    }
    __syncthreads();

    // ---- coalesced writeback ----
    #pragma unroll
    for (int i = 0; i < 2; ++i) {
        int q = i * 256 + t;
        int row = q >> 3, u4 = q & 7;
        if (r0 + row < N_NODES)
            ((uint4*)xh_out)[(size_t)(r0 + row) * 8 + u4] = *(const uint4*)&wt1[row * LROW + 4 * u4];
    }
}

// ---------------- layer-0 dot/L2 (exact f32 from inputs; initializes) -------
__global__ void acc0_kernel(const float* __restrict__ ue, const float* __restrict__ ie,
                            const int* __restrict__ u, const int* __restrict__ ii,
                            const int* __restrict__ jj,
                            float* __restrict__ dui, float* __restrict__ duj,
                            float* __restrict__ l2a) {
    int b = blockIdx.x * 4 + (threadIdx.x >> 6);
    int lane = threadIdx.x & 63;
    float uv = ue[(size_t)u[b] * 64 + lane];
    float pv = ie[(size_t)ii[b] * 64 + lane];
    float nv = ie[(size_t)jj[b] * 64 + lane];
    float a = uv * pv, c = uv * nv, l = uv * uv + pv * pv + nv * nv;
    #pragma unroll
    for (int o = 32; o > 0; o >>= 1) {
        a += __shfl_xor(a, o, 64);
        c += __shfl_xor(c, o, 64);
        l += __shfl_xor(l, o, 64);
    }
    if (lane == 0) { dui[b] = a; duj[b] = c; l2a[b] = l; }
}

// ---------------- per-layer dot/L2 from bf16 embeddings ---------------------
__global__ void accB_kernel(const unsigned int* __restrict__ xh,
                            const int* __restrict__ u, const int* __restrict__ ii,
                            const int* __restrict__ jj,
                            float* __restrict__ dui, float* __restrict__ duj,
                            float* __restrict__ l2a) {
    int t = threadIdx.x;
    int lane = t & 63;
    int half = lane >> 5, p = lane & 31;
    int b = blockIdx.x * 8 + (t >> 6) * 2 + half;
    unsigned ua = xh[(size_t)u[b] * 32 + p];
    unsigned pa = xh[(size_t)(N_USERS + ii[b]) * 32 + p];
    unsigned na = xh[(size_t)(N_USERS + jj[b]) * 32 + p];
    float u0 = blo(ua), u1 = bhi(ua);
    float p0 = blo(pa), p1 = bhi(pa);
    float n0 = blo(na), n1 = bhi(na);
    float a = u0 * p0 + u1 * p1;
    float c = u0 * n0 + u1 * n1;
    float l = u0 * u0 + u1 * u1 + p0 * p0 + p1 * p1 + n0 * n0 + n1 * n1;
    #pragma unroll
    for (int o = 16; o > 0; o >>= 1) {       // reduce within each 32-lane half
        a += __shfl_xor(a, o, 64);
        c += __shfl_xor(c, o, 64);
        l += __shfl_xor(l, o, 64);
    }
    if (p == 0) { dui[b] += a; duj[b] += c; l2a[b] += l; }
}

// ---------------- final loss reduction --------------------------------------
__global__ void final_kernel(const float* __restrict__ dui, const float* __restrict__ duj,
                             const float* __restrict__ l2a, float* __restrict__ out) {
    __shared__ float sh[4];
    int t = threadIdx.x;
    float s = 0.f;
    for (int b = t; b < BATCH; b += 256) {
        float diff = dui[b] - duj[b];
        float ls = (diff >= 0.f) ? -log1pf(expf(-diff)) : (diff - log1pf(expf(diff)));
        s += -ls + REG_C * 0.5f * l2a[b];
    }
    #pragma unroll
    for (int o = 32; o > 0; o >>= 1) s += __shfl_xor(s, o, 64);
    int wave = t >> 6, lane = t & 63;
    if (lane == 0) sh[wave] = s;
    __syncthreads();
    if (t == 0) out[0] = (sh[0] + sh[1] + sh[2] + sh[3]) / (float)BATCH;
}

extern "C" void kernel_launch(void* const* d_in, const int* in_sizes, int n_in,
                              void* d_out, int out_size, void* d_ws, size_t ws_size,
                              hipStream_t stream) {
    const int*   rows     = (const int*)d_in[0];
    const int*   cols     = (const int*)d_in[1];
    const float* vals     = (const float*)d_in[2];
    const float* user_emb = (const float*)d_in[3];
    const float* item_emb = (const float*)d_in[4];
    const float* W_one    = (const float*)d_in[5];
    const float* b_one    = (const float*)d_in[6];
    const float* W_two    = (const float*)d_in[7];
    const float* b_two    = (const float*)d_in[8];
    const int*   u        = (const int*)d_in[9];
    const int*   ii       = (const int*)d_in[10];
    const int*   jj       = (const int*)d_in[11];

    // workspace (~122 MB).  B (f32 sideL, 38.4 MB) aliases binned (40.8 MB),
    // which is dead after p2_sort.
    unsigned int* Xh0 = (unsigned int*)d_ws;                  // 19.2 MB
    unsigned int* Xh1 = Xh0 + (size_t)N_NODES * 32;           // 19.2 MB
    int2* binned      = (int2*)(Xh1 + (size_t)N_NODES * 32);  // 40.8 MB
    float* B          = (float*)binned;                       // alias (post-p2)
    int2* csr         = binned + (size_t)NBK * PADC;          // 40.8 MB
    int*  gcursor     = (int*)(csr + (size_t)NBK * PADC);
    int*  startA      = gcursor + NBK * CSTRIDE;              // 150,016
    int*  cntA        = startA + 150016;                      // 150,016
    float* dui        = (float*)(cntA + 150016);              // 4096
    float* duj        = dui + BATCH;
    float* l2a        = duj + BATCH;

    // CSR build (once; reused for all 3 layers)
    initcur_kernel<<<(NBK + 255) / 256, 256, 0, stream>>>(gcursor);
    p1_bin_kernel<<<(NNZ + P1_EPB - 1) / P1_EPB, 256, 0, stream>>>(rows, cols, vals, gcursor, binned);
    p2_sort_kernel<<<NBK, 256, 0, stream>>>(gcursor, binned, csr, startA, cntA);

    pack_kernel<<<(N_NODES * 8 + 255) / 256, 256, 0, stream>>>(user_emb, item_emb, Xh0);
    acc0_kernel<<<BATCH / 4, 256, 0, stream>>>(user_emb, item_emb, u, ii, jj, dui, duj, l2a);

    unsigned int* xin = Xh0;
    unsigned int* xout = Xh1;
    for (int k = 0; k < 3; ++k) {
        spmm_csr_kernel<<<(N_NODES + 3) / 4, 256, 0, stream>>>(startA, cntA, csr, xin, B);
        dense_kernel<<<(N_NODES + 63) / 64, 256, 0, stream>>>(
            xin, B, W_one + k * 4096, b_one + k * 64,
            W_two + k * 4096, b_two + k * 64, xout);
        accB_kernel<<<BATCH / 8, 256, 0, stream>>>(xout, u, ii, jj, dui, duj, l2a);
        unsigned int* tmp = xin; xin = xout; xout = tmp;
    }

    final_kernel<<<1, 256, 0, stream>>>(dui, duj, l2a, (float*)d_out);
}

// Round 10
// 665.699 us; speedup vs baseline: 2.7369x; 1.2018x over previous
//
#include <hip/hip_runtime.h>
#include <hip/hip_bf16.h>
#include <math.h>

#define N_USERS 100000
#define N_ITEMS 50000
#define N_NODES 150000
#define NNZ     4800000
#define EMB     64
#define BATCH   4096
#define REG_C   1e-5f

// coarse bucketed counting sort
#define ROWB    512                 // rows per bucket (row >> 9)
#define NBK     293                 // ceil(150000/512)
#define PADC    17408               // slots/bucket = mean 16384 + 8 sigma
#define CSTRIDE 16                  // one cursor per 64B line
#define P1_EPB  8192                // edges per block in pass 1

#define LROW    36                  // LDS row stride in uints (16B-aligned rows)

typedef short short8 __attribute__((ext_vector_type(8)));
typedef float f32x4  __attribute__((ext_vector_type(4)));
typedef float f32x2  __attribute__((ext_vector_type(2)));

static __device__ __forceinline__ unsigned short f2bf(float f) {
    unsigned u = __float_as_uint(f);
    u = u + 0x7FFFu + ((u >> 16) & 1u);
    return (unsigned short)(u >> 16);
}
static __device__ __forceinline__ unsigned pk2(float lo, float hi) {
    return (unsigned)f2bf(lo) | ((unsigned)f2bf(hi) << 16);
}
static __device__ __forceinline__ float blo(unsigned a) { return __uint_as_float(a << 16); }
static __device__ __forceinline__ float bhi(unsigned a) { return __uint_as_float(a & 0xFFFF0000u); }

// fp8 e4m3 (OCP) pack/unpack via HW converters
static __device__ __forceinline__ unsigned pkq4(float f0, float f1, float f2, float f3) {
    int v = __builtin_amdgcn_cvt_pk_fp8_f32(f0, f1, 0, false);   // bytes 0-1
    v = __builtin_amdgcn_cvt_pk_fp8_f32(f2, f3, v, true);        // bytes 2-3
    return (unsigned)v;
}

// nontemporal 8B edge load (edges are a pure stream: keep them out of L2)
static __device__ __forceinline__ void eload(const int2* p_, int& c, float& v) {
    unsigned long long w = __builtin_nontemporal_load((const unsigned long long*)p_);
    c = (int)(unsigned)(w & 0xFFFFFFFFu);
    v = __int_as_float((int)(unsigned)(w >> 32));
}

// ---------------- pack ego -> Xh (bf16) + Xq (fp8) --------------------------
__global__ void pack_kernel(const float* __restrict__ ue,
                            const float* __restrict__ ie,
                            unsigned int* __restrict__ xh,
                            unsigned int* __restrict__ xq) {
    int idx = blockIdx.x * 256 + threadIdx.x;     // one 8-dim group per thread
    if (idx >= N_NODES * 8) return;
    const float4* src;
    if (idx < N_USERS * 8) src = (const float4*)ue + (size_t)idx * 2;
    else src = (const float4*)ie + (size_t)(idx - N_USERS * 8) * 2;
    float4 a = src[0], b = src[1];
    uint4 h;
    h.x = pk2(a.x, a.y); h.y = pk2(a.z, a.w);
    h.z = pk2(b.x, b.y); h.w = pk2(b.z, b.w);
    ((uint4*)xh)[idx] = h;
    uint2 q;
    q.x = pkq4(a.x, a.y, a.z, a.w);
    q.y = pkq4(b.x, b.y, b.z, b.w);
    ((uint2*)xq)[idx] = q;
}

// ---------------- cursor init ----------------
__global__ void initcur_kernel(int* __restrict__ gcursor) {
    int b = blockIdx.x * 256 + threadIdx.x;
    if (b < NBK) gcursor[b * CSTRIDE] = b * PADC;
}

// ---------------- pass 1: bin edges into coarse padded regions --------------
__global__ __launch_bounds__(256) void p1_bin_kernel(
    const int* __restrict__ rows, const int* __restrict__ cols,
    const float* __restrict__ vals, int* __restrict__ gcursor,
    int2* __restrict__ binned) {
    __shared__ int hist[NBK];
    __shared__ int base[NBK];
    int t = threadIdx.x;
    int e0 = blockIdx.x * P1_EPB;
    for (int b = t; b < NBK; b += 256) hist[b] = 0;
    __syncthreads();
    for (int i = 0; i < P1_EPB / 256; ++i) {
        int e = e0 + i * 256 + t;
        if (e < NNZ) atomicAdd(&hist[rows[e] >> 9], 1);
    }
    __syncthreads();
    for (int b = t; b < NBK; b += 256) {
        int h = hist[b];
        base[b] = (h > 0) ? atomicAdd(&gcursor[b * CSTRIDE], h) : 0;
        hist[b] = 0;                        // reuse as rank counter
    }
    __syncthreads();
    for (int i = 0; i < P1_EPB / 256; ++i) {
        int e = e0 + i * 256 + t;
        if (e < NNZ) {
            int r = rows[e];
            int b = r >> 9;
            int rk = atomicAdd(&hist[b], 1);
            int pos = base[b] + rk;
            if (pos < (b + 1) * PADC)       // overflow guard (P ~ 0)
                binned[pos] = make_int2(cols[e] | ((r & 511) << 18),
                                        __float_as_int(vals[e]));
        }
    }
}

// ---------------- pass 2: per-bucket row sort via global scatter ------------
__global__ __launch_bounds__(256) void p2_sort_kernel(
    const int* __restrict__ gcursor, const int2* __restrict__ binned,
    int2* __restrict__ csr, int* __restrict__ start, int* __restrict__ cnt) {
    __shared__ int hist[ROWB];
    __shared__ int excl[ROWB];
    int b = blockIdx.x;
    int t = threadIdx.x;
    int bbase = b * PADC;
    int n = gcursor[b * CSTRIDE] - bbase;
    if (n > PADC) n = PADC;
    hist[t] = 0; hist[t + 256] = 0;
    __syncthreads();
    for (int i = t; i < n; i += 256)
        atomicAdd(&hist[(binned[bbase + i].x >> 18) & 511], 1);
    __syncthreads();
    excl[t] = hist[t]; excl[t + 256] = hist[t + 256];
    __syncthreads();
    for (int o = 1; o < ROWB; o <<= 1) {           // Hillis-Steele inclusive, 512 wide
        int i1 = t + 256;
        int v0 = (t >= o) ? excl[t - o] : 0;
        int v1 = (i1 >= o) ? excl[i1 - o] : 0;
        __syncthreads();
        excl[t] += v0; excl[i1] += v1;
        __syncthreads();
    }
    int rowsInB = N_NODES - b * ROWB;
    if (rowsInB > ROWB) rowsInB = ROWB;
    for (int rr = t; rr < ROWB; rr += 256) {
        int s = excl[rr] - hist[rr];               // exclusive
        if (rr < rowsInB) {
            start[b * ROWB + rr] = bbase + s;
            cnt[b * ROWB + rr]   = hist[rr];
        }
        excl[rr] = s;                              // becomes local cursor
    }
    __syncthreads();
    for (int i = t; i < n; i += 256) {
        int2 rec = binned[bbase + i];
        int rl = (rec.x >> 18) & 511;
        int p = atomicAdd(&excl[rl], 1);
        csr[bbase + p] = make_int2(rec.x & 0x3FFFF, rec.y);
    }
}

// ---------------- CSR SpMM: wave/row, fp8 gathers (1 line/edge) -------------
// 4 edges per mem-instruction: lane group eg=lane>>4 serves edge, p=lane&15
// is the uint (4 dims) within the 64B fp8 row.  32 edges in flight.
__global__ __launch_bounds__(256) void spmm_csr_kernel(
    const int* __restrict__ start, const int* __restrict__ cnt,
    const int2* __restrict__ edges, const unsigned int* __restrict__ xq,
    float* __restrict__ out) {
    int row = blockIdx.x * 4 + (threadIdx.x >> 6);
    if (row >= N_NODES) return;
    int lane = threadIdx.x & 63;
    int eg = lane >> 4;
    int p  = lane & 15;
    int s = start[row];
    int n = cnt[row];
    float a0 = 0.f, a1 = 0.f, a2 = 0.f, a3 = 0.f;
    int k = 0;
    for (; k + 32 <= n; k += 32) {                  // unpredicated main: 8 gathers
        int c[8]; float v[8];
        #pragma unroll
        for (int j = 0; j < 8; ++j) eload(&edges[s + k + 4 * j + eg], c[j], v[j]);
        #pragma unroll
        for (int j = 0; j < 8; ++j) {
            unsigned q = xq[(size_t)c[j] * 16 + p];
            f32x2 lo = __builtin_amdgcn_cvt_pk_f32_fp8(q, false);
            f32x2 hi = __builtin_amdgcn_cvt_pk_f32_fp8(q, true);
            a0 = fmaf(v[j], lo[0], a0);
            a1 = fmaf(v[j], lo[1], a1);
            a2 = fmaf(v[j], hi[0], a2);
            a3 = fmaf(v[j], hi[1], a3);
        }
    }
    while (k < n) {                                 // predicated 16-edge blocks
        #pragma unroll
        for (int j = 0; j < 4; ++j) {
            int off = k + 4 * j + eg;
            bool valid = off < n;
            int c; float v;
            eload(&edges[s + (valid ? off : 0)], c, v);
            if (!valid) v = 0.f;
            unsigned q = xq[(size_t)c * 16 + p];
            f32x2 lo = __builtin_amdgcn_cvt_pk_f32_fp8(q, false);
            f32x2 hi = __builtin_amdgcn_cvt_pk_f32_fp8(q, true);
            a0 = fmaf(v, lo[0], a0);
            a1 = fmaf(v, lo[1], a1);
            a2 = fmaf(v, hi[0], a2);
            a3 = fmaf(v, hi[1], a3);
        }
        k += 16;
    }
    a0 += __shfl_xor(a0, 16, 64); a0 += __shfl_xor(a0, 32, 64);
    a1 += __shfl_xor(a1, 16, 64); a1 += __shfl_xor(a1, 32, 64);
    a2 += __shfl_xor(a2, 16, 64); a2 += __shfl_xor(a2, 32, 64);
    a3 += __shfl_xor(a3, 16, 64); a3 += __shfl_xor(a3, 32, 64);
    if (eg == 0)
        ((float4*)out)[(size_t)row * 16 + p] = make_float4(a0, a1, a2, a3);
}

// ---------------- dense v4: MFMA.  OUT = leakyrelu(SLI@W1 + PR@W2 + b) ------
// In-place on xh/xq (each block touches only its own 64-row tile).
__global__ __launch_bounds__(256) void dense_kernel(
    unsigned int* xh, unsigned int* xq, const float* __restrict__ sideL,
    const float* __restrict__ W1, const float* __restrict__ b1,
    const float* __restrict__ W2, const float* __restrict__ b2)
{
    __shared__ unsigned asl[64 * LROW];   // SLI bf16 pairs
    __shared__ unsigned apr[64 * LROW];   // PR  bf16 pairs
    __shared__ unsigned wt1[64 * LROW];   // W1^T [n][k]; reused as out-stage
    __shared__ unsigned wt2[64 * LROW];   // W2^T [n][k]

    int t = threadIdx.x;
    int r0 = blockIdx.x * 64;

    // ---- stage W1/W2 transposed to bf16 [n][k] ----
    #pragma unroll
    for (int i = 0; i < 4; ++i) {
        int idx = i * 256 + t;               // 0..1023 float4s
        int kk = idx >> 4;                   // k row 0..63
        int ng = idx & 15;                   // col group: cols 4ng..4ng+3
        float4 w1v = ((const float4*)W1)[idx];
        float4 w2v = ((const float4*)W2)[idx];
        unsigned short* s1 = (unsigned short*)wt1;
        unsigned short* s2 = (unsigned short*)wt2;
        int c0 = 4 * ng;
        s1[(c0 + 0) * (2 * LROW) + kk] = f2bf(w1v.x);
        s1[(c0 + 1) * (2 * LROW) + kk] = f2bf(w1v.y);
        s1[(c0 + 2) * (2 * LROW) + kk] = f2bf(w1v.z);
        s1[(c0 + 3) * (2 * LROW) + kk] = f2bf(w1v.w);
        s2[(c0 + 0) * (2 * LROW) + kk] = f2bf(w2v.x);
        s2[(c0 + 1) * (2 * LROW) + kk] = f2bf(w2v.y);
        s2[(c0 + 2) * (2 * LROW) + kk] = f2bf(w2v.z);
        s2[(c0 + 3) * (2 * LROW) + kk] = f2bf(w2v.w);
    }

    // ---- stage SLI / PR (bf16 packed) ----
    #pragma unroll
    for (int i = 0; i < 2; ++i) {
        int q = i * 256 + t;                 // 0..511
        int row = q >> 3;                    // 0..63
        int u4 = q & 7;                      // uint4 within row
        uint4 h = make_uint4(0, 0, 0, 0);
        float4 s0 = make_float4(0.f, 0.f, 0.f, 0.f);
        float4 s1 = make_float4(0.f, 0.f, 0.f, 0.f);
        if (r0 + row < N_NODES) {
            h  = ((const uint4*)xh)[(size_t)(r0 + row) * 8 + u4];
            s0 = ((const float4*)sideL)[(size_t)(r0 + row) * 16 + 2 * u4];
            s1 = ((const float4*)sideL)[(size_t)(r0 + row) * 16 + 2 * u4 + 1];
        }
        float x0 = blo(h.x), x1 = bhi(h.x), x2 = blo(h.y), x3 = bhi(h.y);
        float x4 = blo(h.z), x5 = bhi(h.z), x6 = blo(h.w), x7 = bhi(h.w);
        uint4 sa, pa;
        sa.x = pk2(x0 + s0.x, x1 + s0.y); sa.y = pk2(x2 + s0.z, x3 + s0.w);
        sa.z = pk2(x4 + s1.x, x5 + s1.y); sa.w = pk2(x6 + s1.z, x7 + s1.w);
        pa.x = pk2(x0 * s0.x, x1 * s0.y); pa.y = pk2(x2 * s0.z, x3 * s0.w);
        pa.z = pk2(x4 * s1.x, x5 * s1.y); pa.w = pk2(x6 * s1.z, x7 * s1.w);
        *(uint4*)&asl[row * LROW + 4 * u4] = sa;
        *(uint4*)&apr[row * LROW + 4 * u4] = pa;
    }
    __syncthreads();

    // ---- MFMA phase ----
    int l = t & 63, wv = t >> 6;
    int q4 = l >> 4, mr = l & 15;
    int abase = (wv * 16 + mr) * LROW + 4 * q4;
    short8 aS0 = *(const short8*)&asl[abase];
    short8 aS1 = *(const short8*)&asl[abase + 16];
    short8 aP0 = *(const short8*)&apr[abase];
    short8 aP1 = *(const short8*)&apr[abase + 16];

    float lr[4][4];
    float rowss[4] = {0.f, 0.f, 0.f, 0.f};
    #pragma unroll
    for (int nb = 0; nb < 4; ++nb) {
        int wbase = (nb * 16 + mr) * LROW + 4 * q4;
        short8 b10 = *(const short8*)&wt1[wbase];
        short8 b11 = *(const short8*)&wt1[wbase + 16];
        short8 b20 = *(const short8*)&wt2[wbase];
        short8 b21 = *(const short8*)&wt2[wbase + 16];
        f32x4 acc = {0.f, 0.f, 0.f, 0.f};
        acc = __builtin_amdgcn_mfma_f32_16x16x32_bf16(aS0, b10, acc, 0, 0, 0);
        acc = __builtin_amdgcn_mfma_f32_16x16x32_bf16(aS1, b11, acc, 0, 0, 0);
        acc = __builtin_amdgcn_mfma_f32_16x16x32_bf16(aP0, b20, acc, 0, 0, 0);
        acc = __builtin_amdgcn_mfma_f32_16x16x32_bf16(aP1, b21, acc, 0, 0, 0);
        float bias = b1[nb * 16 + mr] + b2[nb * 16 + mr];
        #pragma unroll
        for (int r = 0; r < 4; ++r) {
            float v = acc[r] + bias;
            float lrv = v > 0.f ? v : 0.01f * v;
            lr[nb][r] = lrv;
            rowss[r] += lrv * lrv;
        }
    }
    #pragma unroll
    for (int o = 1; o < 16; o <<= 1) {
        #pragma unroll
        for (int r = 0; r < 4; ++r) rowss[r] += __shfl_xor(rowss[r], o, 64);
    }
    float inv[4];
    #pragma unroll
    for (int r = 0; r < 4; ++r) inv[r] = 1.f / fmaxf(sqrtf(rowss[r]), 1e-12f);

    __syncthreads();                         // all wt1/wt2 reads done
    unsigned short* os = (unsigned short*)wt1;
    #pragma unroll
    for (int nb = 0; nb < 4; ++nb) {
        #pragma unroll
        for (int r = 0; r < 4; ++r) {
            int rloc = wv * 16 + q4 * 4 + r;
            os[rloc * (2 * LROW) + nb * 16 + mr] = f2bf(lr[nb][r] * inv[r]);
        }
    }
    __syncthreads();

    // ---- coalesced writeback: bf16 + fp8 (in place) ----
    #pragma unroll
    for (int i = 0; i < 2; ++i) {
        int q = i * 256 + t;
        int row = q >> 3, u4 = q & 7;
        if (r0 + row < N_NODES) {
            uint4 h = *(const uint4*)&wt1[row * LROW + 4 * u4];
            ((uint4*)xh)[(size_t)(r0 + row) * 8 + u4] = h;
            uint2 qq;
            qq.x = pkq4(blo(h.x), bhi(h.x), blo(h.y), bhi(h.y));
            qq.y = pkq4(blo(h.z), bhi(h.z), blo(h.w), bhi(h.w));
            ((uint2*)xq)[(size_t)(r0 + row) * 8 + u4] = qq;
        }
    }
}

// ---------------- layer-0 dot/L2 (exact f32 from inputs; initializes) -------
__global__ void acc0_kernel(const float* __restrict__ ue, const float* __restrict__ ie,
                            const int* __restrict__ u, const int* __restrict__ ii,
                            const int* __restrict__ jj,
                            float* __restrict__ dui, float* __restrict__ duj,
                            float* __restrict__ l2a) {
    int b = blockIdx.x * 4 + (threadIdx.x >> 6);
    int lane = threadIdx.x & 63;
    float uv = ue[(size_t)u[b] * 64 + lane];
    float pv = ie[(size_t)ii[b] * 64 + lane];
    float nv = ie[(size_t)jj[b] * 64 + lane];
    float a = uv * pv, c = uv * nv, l = uv * uv + pv * pv + nv * nv;
    #pragma unroll
    for (int o = 32; o > 0; o >>= 1) {
        a += __shfl_xor(a, o, 64);
        c += __shfl_xor(c, o, 64);
        l += __shfl_xor(l, o, 64);
    }
    if (lane == 0) { dui[b] = a; duj[b] = c; l2a[b] = l; }
}

// ---------------- per-layer dot/L2 from bf16 embeddings ---------------------
__global__ void accB_kernel(const unsigned int* __restrict__ xh,
                            const int* __restrict__ u, const int* __restrict__ ii,
                            const int* __restrict__ jj,
                            float* __restrict__ dui, float* __restrict__ duj,
                            float* __restrict__ l2a) {
    int t = threadIdx.x;
    int lane = t & 63;
    int half = lane >> 5, p = lane & 31;
    int b = blockIdx.x * 8 + (t >> 6) * 2 + half;
    unsigned ua = xh[(size_t)u[b] * 32 + p];
    unsigned pa = xh[(size_t)(N_USERS + ii[b]) * 32 + p];
    unsigned na = xh[(size_t)(N_USERS + jj[b]) * 32 + p];
    float u0 = blo(ua), u1 = bhi(ua);
    float p0 = blo(pa), p1 = bhi(pa);
    float n0 = blo(na), n1 = bhi(na);
    float a = u0 * p0 + u1 * p1;
    float c = u0 * n0 + u1 * n1;
    float l = u0 * u0 + u1 * u1 + p0 * p0 + p1 * p1 + n0 * n0 + n1 * n1;
    #pragma unroll
    for (int o = 16; o > 0; o >>= 1) {       // reduce within each 32-lane half
        a += __shfl_xor(a, o, 64);
        c += __shfl_xor(c, o, 64);
        l += __shfl_xor(l, o, 64);
    }
    if (p == 0) { dui[b] += a; duj[b] += c; l2a[b] += l; }
}

// ---------------- final loss reduction --------------------------------------
__global__ void final_kernel(const float* __restrict__ dui, const float* __restrict__ duj,
                             const float* __restrict__ l2a, float* __restrict__ out) {
    __shared__ float sh[4];
    int t = threadIdx.x;
    float s = 0.f;
    for (int b = t; b < BATCH; b += 256) {
        float diff = dui[b] - duj[b];
        float ls = (diff >= 0.f) ? -log1pf(expf(-diff)) : (diff - log1pf(expf(diff)));
        s += -ls + REG_C * 0.5f * l2a[b];
    }
    #pragma unroll
    for (int o = 32; o > 0; o >>= 1) s += __shfl_xor(s, o, 64);
    int wave = t >> 6, lane = t & 63;
    if (lane == 0) sh[wave] = s;
    __syncthreads();
    if (t == 0) out[0] = (sh[0] + sh[1] + sh[2] + sh[3]) / (float)BATCH;
}

extern "C" void kernel_launch(void* const* d_in, const int* in_sizes, int n_in,
                              void* d_out, int out_size, void* d_ws, size_t ws_size,
                              hipStream_t stream) {
    const int*   rows     = (const int*)d_in[0];
    const int*   cols     = (const int*)d_in[1];
    const float* vals     = (const float*)d_in[2];
    const float* user_emb = (const float*)d_in[3];
    const float* item_emb = (const float*)d_in[4];
    const float* W_one    = (const float*)d_in[5];
    const float* b_one    = (const float*)d_in[6];
    const float* W_two    = (const float*)d_in[7];
    const float* b_two    = (const float*)d_in[8];
    const int*   u        = (const int*)d_in[9];
    const int*   ii       = (const int*)d_in[10];
    const int*   jj       = (const int*)d_in[11];

    // workspace (~112 MB).  B (f32 sideL, 38.4 MB) aliases binned (40.8 MB),
    // which is dead after p2_sort.  Xh/Xq are single buffers (dense is
    // tile-in-place; spmm reads only Xq, dense writes Xq after spmm is done).
    unsigned int* Xh  = (unsigned int*)d_ws;                  // 19.2 MB bf16
    unsigned int* Xq  = Xh + (size_t)N_NODES * 32;            //  9.6 MB fp8
    int2* binned      = (int2*)(Xq + (size_t)N_NODES * 16);   // 40.8 MB
    float* B          = (float*)binned;                       // alias (post-p2)
    int2* csr         = binned + (size_t)NBK * PADC;          // 40.8 MB
    int*  gcursor     = (int*)(csr + (size_t)NBK * PADC);
    int*  startA      = gcursor + NBK * CSTRIDE;              // 150,016
    int*  cntA        = startA + 150016;                      // 150,016
    float* dui        = (float*)(cntA + 150016);              // 4096
    float* duj        = dui + BATCH;
    float* l2a        = duj + BATCH;

    // CSR build (once; reused for all 3 layers)
    initcur_kernel<<<(NBK + 255) / 256, 256, 0, stream>>>(gcursor);
    p1_bin_kernel<<<(NNZ + P1_EPB - 1) / P1_EPB, 256, 0, stream>>>(rows, cols, vals, gcursor, binned);
    p2_sort_kernel<<<NBK, 256, 0, stream>>>(gcursor, binned, csr, startA, cntA);

    pack_kernel<<<(N_NODES * 8 + 255) / 256, 256, 0, stream>>>(user_emb, item_emb, Xh, Xq);
    acc0_kernel<<<BATCH / 4, 256, 0, stream>>>(user_emb, item_emb, u, ii, jj, dui, duj, l2a);

    for (int k = 0; k < 3; ++k) {
        spmm_csr_kernel<<<(N_NODES + 3) / 4, 256, 0, stream>>>(startA, cntA, csr, Xq, B);
        dense_kernel<<<(N_NODES + 63) / 64, 256, 0, stream>>>(
            Xh, Xq, B, W_one + k * 4096, b_one + k * 64,
            W_two + k * 4096, b_two + k * 64);
        accB_kernel<<<BATCH / 8, 256, 0, stream>>>(Xh, u, ii, jj, dui, duj, l2a);
    }

    final_kernel<<<1, 256, 0, stream>>>(dui, duj, l2a, (float*)d_out);
}